// Round 11
// baseline (6210.854 us; speedup 1.0000x reference)
//
#include <hip/hip_runtime.h>
#include <hip/hip_fp16.h>

// Persistent fused GRU + value head, MI355X (gfx950).
// T=512,B=256,I=64,H=512.
// R24: FEWER FLAG PUBLISHERS. 64 blocks x 576 threads (8 MFMA waves + 1
// service wave); 16 groups x 4 blocks x 128 hidden units. Per-WAVE work is
// bit-identical to the champion (each wave = 16 units, same fragments, same
// FP order, same slab layout, same MALL scopes). Protocol change: ONE flag
// per BLOCK (4 publishers/group instead of 32), published after
// {per-wave vmcnt(0) -> __syncthreads} joins all 8 waves' store-acks via the
// ~100cy HW barrier. Rationale: R22 measured each ballot-wait at ~2000+cy
// even with big slack -> dominated by straggler-max over publisher
// propagation jitter, which grows with publisher count. 4 flags sit in one
// 16B cluster -> poll reads 1 line. Group members share blk&15 => blk%8 =>
// same XCD (champion's placement).
// HARD RULE: every VMEM-load asm block contains its own s_waitcnt.

#define T_  512
#define B_  256
#define I_  64
#define H_  512
#define NBG 16
#define BT  16                  // batch rows per group
#define NMW 8                   // MFMA waves per block (4 wave-pairs)
#define BLOCK 576               // 8 MFMA waves + 1 service wave
#define NSL 32                  // value-head slices

typedef _Float16 f16;
typedef _Float16 f16x8 __attribute__((ext_vector_type(8)));
typedef float    f32x4 __attribute__((ext_vector_type(4)));
typedef unsigned int u32x2 __attribute__((ext_vector_type(2)));

__device__ __forceinline__ float sigmoid_f(float x) { return 1.f / (1.f + __expf(-x)); }
__device__ __forceinline__ float tanh_f(float x) {
    float e2 = __expf(2.f * x);
    return 1.f - 2.f / (e2 + 1.f);
}

__global__ __launch_bounds__(BLOCK, 1) void gru_persistent(
    const float* __restrict__ X, const float* __restrict__ Wih,
    const float* __restrict__ Whh, const float* __restrict__ bih,
    const float* __restrict__ bhh, const float* __restrict__ vw,
    const float* __restrict__ bias, float* __restrict__ Vout,
    f16* __restrict__ hbuf, unsigned int* __restrict__ flags,
    float* __restrict__ part, const int use_part)
{
    const int blk  = blockIdx.x;            // 64 blocks
    const int g    = blk & 15;              // group: members share blk%8 -> same XCD
    const int jb   = blk >> 4;              // block-within-group 0..3
    const int b0   = g * BT;
    const int tid  = threadIdx.x;
    const int wv   = tid >> 6;              // 0..8
    const int lane = tid & 63;
    const int quad = lane >> 4;
    const int mrow = lane & 15;

    __shared__ __align__(16) f16 sh_x[2][BT][I_ + 8];   // X_t ping-pong (f16), padded
    unsigned int* gflags = flags + (size_t)g * 32;       // one 128B line per group

    if (wv < NMW) {
        // ===== MFMA waves: wave = 16 hidden units, exactly as champion =====
        // pair p = wv>>1, w01 = wv&1; global slice jg = jb*4 + p.
        const int p   = wv >> 1;
        const int w01 = wv & 1;
        const int jg  = jb * 4 + p;
        f16x8 wh[3][16];
        f16x8 wxA[3][2];
        const int um = 32 * jg + w01 * 16 + mrow;
        #pragma unroll
        for (int g3 = 0; g3 < 3; g3++) {
            const size_t grow = (size_t)(g3 * H_ + um);
            #pragma unroll
            for (int kt = 0; kt < 16; kt++) {
                const float* src = Whh + grow * H_ + kt * 32 + quad * 8;
                #pragma unroll
                for (int e = 0; e < 8; e++) wh[g3][kt][e] = (f16)src[e];
            }
            #pragma unroll
            for (int kt = 0; kt < 2; kt++) {
                const float* src = Wih + grow * I_ + kt * 32 + quad * 8;
                #pragma unroll
                for (int e = 0; e < 8; e++) wxA[g3][kt][e] = (f16)src[e];
            }
        }
        float b_r4[4], b_z4[4], b_ni4[4], b_nh4[4], vw4[4];
        #pragma unroll
        for (int r = 0; r < 4; r++) {
            const int ub = 32 * jg + w01 * 16 + quad * 4 + r;
            b_r4[r]  = bih[ub] + bhh[ub];
            b_z4[r]  = bih[H_ + ub] + bhh[H_ + ub];
            b_ni4[r] = bih[2 * H_ + ub];
            b_nh4[r] = bhh[2 * H_ + ub];
            vw4[r]   = vw[ub];
        }
        float hprev[4] = {0.f, 0.f, 0.f, 0.f};   // fp32 anchor for z*h (t=0 zeros)
        const int sl = 8 * jb + wv;              // = jg*2 + w01
        const float bias0 = bias[0];
        const f32x4 zero = {0.f, 0.f, 0.f, 0.f};
        // producer h offset (identical layout to champion, j -> jg, wv -> w01)
        const size_t hoff = (size_t)((4 * jg + 2 * w01 + (quad >> 1)) * 128
                                     + mrow * 8 + (quad & 1) * 4);
        unsigned int* blkflag = gflags + jb;     // ONE flag per block

        __syncthreads();   // init: service staged X_0 into slot 0

        // ---- x-GEMM for t=0 (slot 0), loop-carried ----
        f32x4 xr, xz, xni;
        {
            f16x8 bx0 = *(const f16x8*)&sh_x[0][mrow][quad * 8];
            f16x8 bx1 = *(const f16x8*)&sh_x[0][mrow][32 + quad * 8];
            xr  = __builtin_amdgcn_mfma_f32_16x16x32_f16(wxA[0][0], bx0, zero, 0, 0, 0);
            xz  = __builtin_amdgcn_mfma_f32_16x16x32_f16(wxA[1][0], bx0, zero, 0, 0, 0);
            xni = __builtin_amdgcn_mfma_f32_16x16x32_f16(wxA[2][0], bx0, zero, 0, 0, 0);
            xr  = __builtin_amdgcn_mfma_f32_16x16x32_f16(wxA[0][1], bx1, xr,  0, 0, 0);
            xz  = __builtin_amdgcn_mfma_f32_16x16x32_f16(wxA[1][1], bx1, xz,  0, 0, 0);
            xni = __builtin_amdgcn_mfma_f32_16x16x32_f16(wxA[2][1], bx1, xni, 0, 0, 0);
        }

        #pragma unroll 1
        for (int t = 0; t < T_; t++) {
            // ---- 1. ballot poll over 4 block-flags (one 16B cluster) ----
            if (t > 0) {
                const unsigned target = (unsigned)t;
                for (;;) {
                    unsigned v = target;
                    if (lane < 4) {
                        const unsigned int* fp = gflags + lane;
                        asm volatile("global_load_dword %0, %1, off sc0 sc1\n\t"
                                     "s_waitcnt vmcnt(0)"
                                     : "=v"(v) : "v"(fp) : "memory");
                    }
                    if (__ballot(v >= target) == ~0ull) break;
                }
            }

            // ---- 2. h_{t-1} fragments: 16 x 1KB loads, wait INSIDE asm ----
            f16x8 afr[16];
            const char* pb = (const char*)(hbuf
                           + ((size_t)((t & 1) ^ 1) * NBG + g) * 8192)
                           + quad * 256 + mrow * 16;
            asm volatile(
                "global_load_dwordx4 %0, %16, off sc0 sc1\n\t"
                "global_load_dwordx4 %1, %16, off offset:1024 sc0 sc1\n\t"
                "global_load_dwordx4 %2, %16, off offset:2048 sc0 sc1\n\t"
                "global_load_dwordx4 %3, %16, off offset:3072 sc0 sc1\n\t"
                "global_load_dwordx4 %4, %17, off sc0 sc1\n\t"
                "global_load_dwordx4 %5, %17, off offset:1024 sc0 sc1\n\t"
                "global_load_dwordx4 %6, %17, off offset:2048 sc0 sc1\n\t"
                "global_load_dwordx4 %7, %17, off offset:3072 sc0 sc1\n\t"
                "global_load_dwordx4 %8, %18, off sc0 sc1\n\t"
                "global_load_dwordx4 %9, %18, off offset:1024 sc0 sc1\n\t"
                "global_load_dwordx4 %10, %18, off offset:2048 sc0 sc1\n\t"
                "global_load_dwordx4 %11, %18, off offset:3072 sc0 sc1\n\t"
                "global_load_dwordx4 %12, %19, off sc0 sc1\n\t"
                "global_load_dwordx4 %13, %19, off offset:1024 sc0 sc1\n\t"
                "global_load_dwordx4 %14, %19, off offset:2048 sc0 sc1\n\t"
                "global_load_dwordx4 %15, %19, off offset:3072 sc0 sc1\n\t"
                "s_waitcnt vmcnt(0)"
                : "=&v"(afr[0]), "=&v"(afr[1]), "=&v"(afr[2]), "=&v"(afr[3]),
                  "=&v"(afr[4]), "=&v"(afr[5]), "=&v"(afr[6]), "=&v"(afr[7]),
                  "=&v"(afr[8]), "=&v"(afr[9]), "=&v"(afr[10]), "=&v"(afr[11]),
                  "=&v"(afr[12]), "=&v"(afr[13]), "=&v"(afr[14]), "=&v"(afr[15])
                : "v"(pb), "v"(pb + 4096), "v"(pb + 8192), "v"(pb + 12288)
                : "memory");

            // ---- 3. h-MFMA chain seeded by the loop-carried x-GEMM result ----
            f32x4 a_r = xr, a_z = xz, a_ni = xni;
            f32x4 a_nh = zero;
            #pragma unroll
            for (int kt = 0; kt < 16; kt++) {
                a_r  = __builtin_amdgcn_mfma_f32_16x16x32_f16(wh[0][kt], afr[kt], a_r,  0, 0, 0);
                a_z  = __builtin_amdgcn_mfma_f32_16x16x32_f16(wh[1][kt], afr[kt], a_z,  0, 0, 0);
                a_nh = __builtin_amdgcn_mfma_f32_16x16x32_f16(wh[2][kt], afr[kt], a_nh, 0, 0, 0);
            }

            // ---- 4. gates; one 8B fragment-major h-store/lane ----
            float hn[4];
            union { f16 h[4]; u32x2 v; } pk;
            #pragma unroll
            for (int r = 0; r < 4; r++) {
                float rg = sigmoid_f(a_r[r] + b_r4[r]);
                float zg = sigmoid_f(a_z[r] + b_z4[r]);
                float ng = tanh_f(a_ni[r] + b_ni4[r] + rg * (a_nh[r] + b_nh4[r]));
                hn[r] = (1.f - zg) * ng + zg * hprev[r];
                hprev[r] = hn[r];
                pk.h[r] = (f16)hn[r];
            }
            {
                f16* hp = hbuf + ((size_t)(t & 1) * NBG + g) * 8192 + hoff;
                asm volatile("global_store_dwordx2 %0, %1, off sc0 sc1"
                             :: "v"(hp), "v"(pk.v) : "memory");
            }
            // value-head partial overlaps the store's flight time
            float s = hn[0] * vw4[0] + hn[1] * vw4[1] + hn[2] * vw4[2] + hn[3] * vw4[3];
            s += __shfl_xor(s, 16);
            s += __shfl_xor(s, 32);

            // ---- 5. barrier1 (X fence) + x-GEMM(t+1) overlap the store drain ----
            __syncthreads();
            if (t + 1 < T_) {
                f16x8 bx0 = *(const f16x8*)&sh_x[(t + 1) & 1][mrow][quad * 8];
                f16x8 bx1 = *(const f16x8*)&sh_x[(t + 1) & 1][mrow][32 + quad * 8];
                xr  = __builtin_amdgcn_mfma_f32_16x16x32_f16(wxA[0][0], bx0, zero, 0, 0, 0);
                xz  = __builtin_amdgcn_mfma_f32_16x16x32_f16(wxA[1][0], bx0, zero, 0, 0, 0);
                xni = __builtin_amdgcn_mfma_f32_16x16x32_f16(wxA[2][0], bx0, zero, 0, 0, 0);
                xr  = __builtin_amdgcn_mfma_f32_16x16x32_f16(wxA[0][1], bx1, xr,  0, 0, 0);
                xz  = __builtin_amdgcn_mfma_f32_16x16x32_f16(wxA[1][1], bx1, xz,  0, 0, 0);
                xni = __builtin_amdgcn_mfma_f32_16x16x32_f16(wxA[2][1], bx1, xni, 0, 0, 0);
            }
            __builtin_amdgcn_sched_barrier(0);   // pin x-GEMM before the ack

            // ---- 6. per-wave ack -> barrier2 joins all 8 waves -> 1 publish ----
            asm volatile("s_waitcnt vmcnt(0)" ::: "memory");   // own h at MALL
            __syncthreads();                                    // all waves acked
            if (tid == 0)
                __hip_atomic_store(blkflag, (unsigned)(t + 1),
                                   __ATOMIC_RELAXED, __HIP_MEMORY_SCOPE_AGENT);
            if (quad == 0) {
                if (use_part) part[(size_t)sl * (T_ * B_) + (size_t)t * B_ + b0 + mrow] = s;
                else atomicAdd(&Vout[(size_t)t * B_ + b0 + mrow], s + (sl == 0 ? bias0 : 0.f));
            }
        }
    } else {
        // ============== service wave: X_{t+1} -> LDS ping-pong (off-path) ==============
        const int bb = lane >> 2, seg = (lane & 3) * 16;
        {   // stage X_0 -> slot 0
            const float* xs = X + (size_t)(b0 + bb) * I_ + seg;
            const float4 x0 = *(const float4*)(xs + 0),  x1 = *(const float4*)(xs + 4);
            const float4 x2 = *(const float4*)(xs + 8),  x3 = *(const float4*)(xs + 12);
            f16* dst = &sh_x[0][bb][seg];
            f16x8 p0 = {(f16)x0.x,(f16)x0.y,(f16)x0.z,(f16)x0.w,(f16)x1.x,(f16)x1.y,(f16)x1.z,(f16)x1.w};
            f16x8 p1 = {(f16)x2.x,(f16)x2.y,(f16)x2.z,(f16)x2.w,(f16)x3.x,(f16)x3.y,(f16)x3.z,(f16)x3.w};
            *(f16x8*)dst = p0; *(f16x8*)(dst + 8) = p1;
        }
        __syncthreads();   // init barrier
        #pragma unroll 1
        for (int t = 0; t < T_; t++) {
            if (t + 1 < T_) {
                const float* xs = X + (size_t)(t + 1) * (B_ * I_) + (size_t)(b0 + bb) * I_ + seg;
                const float4 x0 = *(const float4*)(xs + 0),  x1 = *(const float4*)(xs + 4);
                const float4 x2 = *(const float4*)(xs + 8),  x3 = *(const float4*)(xs + 12);
                f16* dst = &sh_x[(t + 1) & 1][bb][seg];
                f16x8 p0 = {(f16)x0.x,(f16)x0.y,(f16)x0.z,(f16)x0.w,(f16)x1.x,(f16)x1.y,(f16)x1.z,(f16)x1.w};
                f16x8 p1 = {(f16)x2.x,(f16)x2.y,(f16)x2.z,(f16)x2.w,(f16)x3.x,(f16)x3.y,(f16)x3.z,(f16)x3.w};
                *(f16x8*)dst = p0; *(f16x8*)(dst + 8) = p1;
            }
            __syncthreads();   // barrier1
            __syncthreads();   // barrier2 (ack join; nothing to do here)
        }
    }
}

__global__ __launch_bounds__(256) void value_reduce(
    const float* __restrict__ part, const float* __restrict__ bias,
    float* __restrict__ Vout)
{
    const int i = blockIdx.x * 256 + threadIdx.x;   // i < T_*B_
    float s = bias[0];
    #pragma unroll
    for (int sl = 0; sl < NSL; sl++) s += part[(size_t)sl * (T_ * B_) + i];
    Vout[i] = s;
}

extern "C" void kernel_launch(void* const* d_in, const int* in_sizes, int n_in,
                              void* d_out, int out_size, void* d_ws, size_t ws_size,
                              hipStream_t stream) {
    const float* X    = (const float*)d_in[0];
    const float* Wih  = (const float*)d_in[1];
    const float* Whh  = (const float*)d_in[2];
    const float* bih  = (const float*)d_in[3];
    const float* bhh  = (const float*)d_in[4];
    const float* vw   = (const float*)d_in[5];
    const float* bias = (const float*)d_in[6];
    float* Vout = (float*)d_out;

    f16* hbuf = (f16*)d_ws;
    const size_t hbytes    = (size_t)2 * B_ * H_ * sizeof(f16);        // 512 KB
    const size_t flagbytes = (size_t)NBG * 32 * sizeof(unsigned);      // 2 KB (1 line/group)
    unsigned int* flags = (unsigned int*)((char*)d_ws + hbytes);
    float* part = (float*)((char*)d_ws + hbytes + flagbytes);
    const size_t partbytes = (size_t)NSL * T_ * B_ * sizeof(float);    // 16.8 MB
    const int use_part = (ws_size >= hbytes + flagbytes + partbytes) ? 1 : 0;

    hipMemsetAsync(d_ws, 0, hbytes + flagbytes, stream);   // hbuf zeros (t=0) + flags
    if (!use_part)
        hipMemsetAsync(d_out, 0, (size_t)out_size * sizeof(float), stream);

    gru_persistent<<<64, BLOCK, 0, stream>>>(X, Wih, Whh, bih, bhh, vw, bias,
                                             Vout, hbuf, flags, part, use_part);
    if (use_part)
        value_reduce<<<(T_ * B_) / 256, 256, 0, stream>>>(part, bias, Vout);
}

// Round 12
// 1425.577 us; speedup vs baseline: 4.3567x; 4.3567x over previous
//
#include <hip/hip_runtime.h>
#include <hip/hip_fp16.h>

// Persistent fused GRU + value head, MI355X (gfx950).
// T=512,B=256,I=64,H=512. 256 blocks = 16 batch groups x 16 hidden slices.
// R25 = R19 VERBATIM — final restore of the session's best green
// (harness 1384us; champion protocol + tail reorder).
// Session conclusion: step time is a cross-XCD sync-latency floor
// (straggler-max over 32 flag publishers ~2000-2400cy + 1 MALL load RT
// ~700cy + publish ~1500cy + compute ~800cy), NOT a memory/compute
// roofline (HBM 2.3%, MfmaUtil 6.8%). Avenues tested and closed:
//   - compute reorders (R18/R19): green but neutral — nothing overlaps the
//     serial MALL round trips except other round trips;
//   - L2-scope (sc0-only) exchange (R15/R20): falsified on HW — stale reads
//     with reproducible absmax signature even with coupled waits;
//   - self-validating tagged slab (R21): 2x volume + 64 in-flight VGPRs ->
//     spills/timeout;
//   - two-group interleave (R22): -47% — doubles the per-iteration ballot
//     straggler-max, which dominates;
//   - fewer publishers via 8-wave blocks (R24): -344% — 192-VGPR weight
//     arrays spill at 576 threads/block (VGPR_Count fell to 84).
// HARD RULE (R15/R17): every VMEM-load asm block contains its own s_waitcnt;
// decoupling issue from wait lets the allocator touch in-flight destination
// VGPRs at this register pressure -> silent corruption.

#define T_  512
#define B_  256
#define I_  64
#define H_  512
#define NBG 16
#define BT  16                  // batch rows per group
#define HS  32                  // hidden units per block
#define BLOCK 192
#define NSL 32                  // value-head slices (j,wv)

typedef _Float16 f16;
typedef _Float16 f16x8 __attribute__((ext_vector_type(8)));
typedef float    f32x4 __attribute__((ext_vector_type(4)));
typedef unsigned int u32x2 __attribute__((ext_vector_type(2)));

__device__ __forceinline__ float sigmoid_f(float x) { return 1.f / (1.f + __expf(-x)); }
__device__ __forceinline__ float tanh_f(float x) {
    float e2 = __expf(2.f * x);
    return 1.f - 2.f / (e2 + 1.f);
}

__global__ __launch_bounds__(BLOCK, 1) void gru_persistent(
    const float* __restrict__ X, const float* __restrict__ Wih,
    const float* __restrict__ Whh, const float* __restrict__ bih,
    const float* __restrict__ bhh, const float* __restrict__ vw,
    const float* __restrict__ bias, float* __restrict__ Vout,
    f16* __restrict__ hbuf, unsigned int* __restrict__ flags,
    float* __restrict__ part, const int use_part)
{
    const int blk  = blockIdx.x;
    const int g    = (blk & 7) * 2 + (blk >> 7);   // group members share blk%8
    const int j    = (blk >> 3) & 15;
    const int b0   = g * BT;
    const int tid  = threadIdx.x;
    const int wv   = tid >> 6;
    const int lane = tid & 63;
    const int quad = lane >> 4;
    const int mrow = lane & 15;

    __shared__ __align__(16) f16 sh_x[2][BT][I_ + 8];   // X_t ping-pong (f16), padded
    unsigned int* gflags = flags + (size_t)g * 32;       // one 128B line per group

    if (wv < 2) {
        // ============ MFMA waves: weights=A (units on M), h/x=B (batch on N) ============
        // A[m=lane&15 -> unit][k=quad*8+e]; D: row=quad*4+r -> unit, col=lane&15 -> batch
        f16x8 wh[3][16];
        f16x8 wxA[3][2];
        const int um = HS * j + wv * 16 + mrow;
        #pragma unroll
        for (int g3 = 0; g3 < 3; g3++) {
            const size_t grow = (size_t)(g3 * H_ + um);
            #pragma unroll
            for (int kt = 0; kt < 16; kt++) {
                const float* src = Whh + grow * H_ + kt * 32 + quad * 8;
                #pragma unroll
                for (int e = 0; e < 8; e++) wh[g3][kt][e] = (f16)src[e];
            }
            #pragma unroll
            for (int kt = 0; kt < 2; kt++) {
                const float* src = Wih + grow * I_ + kt * 32 + quad * 8;
                #pragma unroll
                for (int e = 0; e < 8; e++) wxA[g3][kt][e] = (f16)src[e];
            }
        }
        float b_r4[4], b_z4[4], b_ni4[4], b_nh4[4], vw4[4];
        #pragma unroll
        for (int r = 0; r < 4; r++) {
            const int ub = HS * j + wv * 16 + quad * 4 + r;
            b_r4[r]  = bih[ub] + bhh[ub];
            b_z4[r]  = bih[H_ + ub] + bhh[H_ + ub];
            b_ni4[r] = bih[2 * H_ + ub];
            b_nh4[r] = bhh[2 * H_ + ub];
            vw4[r]   = vw[ub];
        }
        float hprev[4] = {0.f, 0.f, 0.f, 0.f};   // fp32 anchor for z*h (t=0 zeros)
        unsigned int* myflag = gflags + (j * 2 + wv);
        const int sl = j * 2 + wv;
        const float bias0 = bias[0];
        const f32x4 zero = {0.f, 0.f, 0.f, 0.f};

        __syncthreads();   // init: service staged X_0 into slot 0

        // ---- x-GEMM for t=0 (slot 0), loop-carried into the first iteration ----
        f32x4 xr, xz, xni;
        {
            f16x8 bx0 = *(const f16x8*)&sh_x[0][mrow][quad * 8];
            f16x8 bx1 = *(const f16x8*)&sh_x[0][mrow][32 + quad * 8];
            xr  = __builtin_amdgcn_mfma_f32_16x16x32_f16(wxA[0][0], bx0, zero, 0, 0, 0);
            xz  = __builtin_amdgcn_mfma_f32_16x16x32_f16(wxA[1][0], bx0, zero, 0, 0, 0);
            xni = __builtin_amdgcn_mfma_f32_16x16x32_f16(wxA[2][0], bx0, zero, 0, 0, 0);
            xr  = __builtin_amdgcn_mfma_f32_16x16x32_f16(wxA[0][1], bx1, xr,  0, 0, 0);
            xz  = __builtin_amdgcn_mfma_f32_16x16x32_f16(wxA[1][1], bx1, xz,  0, 0, 0);
            xni = __builtin_amdgcn_mfma_f32_16x16x32_f16(wxA[2][1], bx1, xni, 0, 0, 0);
        }

        #pragma unroll 1
        for (int t = 0; t < T_; t++) {
            // ---- 1. ballot poll: one coalesced 128B line read per iteration
            //         (champion-exact: wait INSIDE the asm block) ----
            if (t > 0) {
                const unsigned target = (unsigned)t;
                for (;;) {
                    unsigned v = target;
                    if (lane < 32) {
                        const unsigned int* fp = gflags + lane;
                        asm volatile("global_load_dword %0, %1, off sc0 sc1\n\t"
                                     "s_waitcnt vmcnt(0)"
                                     : "=v"(v) : "v"(fp) : "memory");
                    }
                    if (__ballot(v >= target) == ~0ull) break;
                }
            }

            // ---- 2. h_{t-1} fragments: fragment-major slab, 16 x 1KB-contiguous
            //         loads, vmcnt(0) INSIDE the asm (hard rule) ----
            f16x8 afr[16];
            const char* pb = (const char*)(hbuf
                           + ((size_t)((t & 1) ^ 1) * NBG + g) * 8192)
                           + quad * 256 + mrow * 16;
            asm volatile(
                "global_load_dwordx4 %0, %16, off sc0 sc1\n\t"
                "global_load_dwordx4 %1, %16, off offset:1024 sc0 sc1\n\t"
                "global_load_dwordx4 %2, %16, off offset:2048 sc0 sc1\n\t"
                "global_load_dwordx4 %3, %16, off offset:3072 sc0 sc1\n\t"
                "global_load_dwordx4 %4, %17, off sc0 sc1\n\t"
                "global_load_dwordx4 %5, %17, off offset:1024 sc0 sc1\n\t"
                "global_load_dwordx4 %6, %17, off offset:2048 sc0 sc1\n\t"
                "global_load_dwordx4 %7, %17, off offset:3072 sc0 sc1\n\t"
                "global_load_dwordx4 %8, %18, off sc0 sc1\n\t"
                "global_load_dwordx4 %9, %18, off offset:1024 sc0 sc1\n\t"
                "global_load_dwordx4 %10, %18, off offset:2048 sc0 sc1\n\t"
                "global_load_dwordx4 %11, %18, off offset:3072 sc0 sc1\n\t"
                "global_load_dwordx4 %12, %19, off sc0 sc1\n\t"
                "global_load_dwordx4 %13, %19, off offset:1024 sc0 sc1\n\t"
                "global_load_dwordx4 %14, %19, off offset:2048 sc0 sc1\n\t"
                "global_load_dwordx4 %15, %19, off offset:3072 sc0 sc1\n\t"
                "s_waitcnt vmcnt(0)"
                : "=&v"(afr[0]), "=&v"(afr[1]), "=&v"(afr[2]), "=&v"(afr[3]),
                  "=&v"(afr[4]), "=&v"(afr[5]), "=&v"(afr[6]), "=&v"(afr[7]),
                  "=&v"(afr[8]), "=&v"(afr[9]), "=&v"(afr[10]), "=&v"(afr[11]),
                  "=&v"(afr[12]), "=&v"(afr[13]), "=&v"(afr[14]), "=&v"(afr[15])
                : "v"(pb), "v"(pb + 4096), "v"(pb + 8192), "v"(pb + 12288)
                : "memory");

            // ---- 3. h-MFMA chain seeded by the loop-carried x-GEMM result ----
            f32x4 a_r = xr, a_z = xz, a_ni = xni;
            f32x4 a_nh = zero;
            #pragma unroll
            for (int kt = 0; kt < 16; kt++) {
                a_r  = __builtin_amdgcn_mfma_f32_16x16x32_f16(wh[0][kt], afr[kt], a_r,  0, 0, 0);
                a_z  = __builtin_amdgcn_mfma_f32_16x16x32_f16(wh[1][kt], afr[kt], a_z,  0, 0, 0);
                a_nh = __builtin_amdgcn_mfma_f32_16x16x32_f16(wh[2][kt], afr[kt], a_nh, 0, 0, 0);
            }

            // ---- 4. gates in registers; one 8B fragment-major h-store/lane ----
            float hn[4];
            union { f16 h[4]; u32x2 v; } pk;
            #pragma unroll
            for (int r = 0; r < 4; r++) {
                float rg = sigmoid_f(a_r[r] + b_r4[r]);
                float zg = sigmoid_f(a_z[r] + b_z4[r]);
                float ng = tanh_f(a_ni[r] + b_ni4[r] + rg * (a_nh[r] + b_nh4[r]));
                hn[r] = (1.f - zg) * ng + zg * hprev[r];
                hprev[r] = hn[r];
                pk.h[r] = (f16)hn[r];
            }
            {
                // h[batch=mrow][u=32j+16wv+4quad+r] -> idx=(u>>3)*128 + mrow*8 + (u&7)
                f16* hp = hbuf + ((size_t)(t & 1) * NBG + g) * 8192
                        + (size_t)((4 * j + 2 * wv + (quad >> 1)) * 128
                                   + mrow * 8 + (quad & 1) * 4);
                asm volatile("global_store_dwordx2 %0, %1, off sc0 sc1"
                             :: "v"(hp), "v"(pk.v) : "memory");
            }
            // value-head partial overlaps the store's flight time
            float s = hn[0] * vw4[0] + hn[1] * vw4[1] + hn[2] * vw4[2] + hn[3] * vw4[3];
            s += __shfl_xor(s, 16);
            s += __shfl_xor(s, 32);

            // ---- 5. barrier + next-step x-GEMM overlap the h-store drain ----
            __syncthreads();   // X ping-pong fence (service wave long done)
            if (t + 1 < T_) {
                f16x8 bx0 = *(const f16x8*)&sh_x[(t + 1) & 1][mrow][quad * 8];
                f16x8 bx1 = *(const f16x8*)&sh_x[(t + 1) & 1][mrow][32 + quad * 8];
                xr  = __builtin_amdgcn_mfma_f32_16x16x32_f16(wxA[0][0], bx0, zero, 0, 0, 0);
                xz  = __builtin_amdgcn_mfma_f32_16x16x32_f16(wxA[1][0], bx0, zero, 0, 0, 0);
                xni = __builtin_amdgcn_mfma_f32_16x16x32_f16(wxA[2][0], bx0, zero, 0, 0, 0);
                xr  = __builtin_amdgcn_mfma_f32_16x16x32_f16(wxA[0][1], bx1, xr,  0, 0, 0);
                xz  = __builtin_amdgcn_mfma_f32_16x16x32_f16(wxA[1][1], bx1, xz,  0, 0, 0);
                xni = __builtin_amdgcn_mfma_f32_16x16x32_f16(wxA[2][1], bx1, xni, 0, 0, 0);
            }
            __builtin_amdgcn_sched_barrier(0);   // pin x-GEMM before the ack

            // ---- 6. ack (mostly drained by now) -> flag -> part-store ----
            asm volatile("s_waitcnt vmcnt(0)" ::: "memory");   // h at MALL before flag
            if (lane == 0)
                __hip_atomic_store(myflag, (unsigned)(t + 1),
                                   __ATOMIC_RELAXED, __HIP_MEMORY_SCOPE_AGENT);
            if (quad == 0) {
                if (use_part) part[(size_t)sl * (T_ * B_) + (size_t)t * B_ + b0 + mrow] = s;
                else atomicAdd(&Vout[(size_t)t * B_ + b0 + mrow], s + (sl == 0 ? bias0 : 0.f));
            }
        }
    } else {
        // ============== service wave: X_{t+1} -> LDS ping-pong (off-path) ==============
        const int bb = lane >> 2, seg = (lane & 3) * 16;
        {   // stage X_0 -> slot 0
            const float* xs = X + (size_t)(b0 + bb) * I_ + seg;
            const float4 x0 = *(const float4*)(xs + 0),  x1 = *(const float4*)(xs + 4);
            const float4 x2 = *(const float4*)(xs + 8),  x3 = *(const float4*)(xs + 12);
            f16* dst = &sh_x[0][bb][seg];
            f16x8 p0 = {(f16)x0.x,(f16)x0.y,(f16)x0.z,(f16)x0.w,(f16)x1.x,(f16)x1.y,(f16)x1.z,(f16)x1.w};
            f16x8 p1 = {(f16)x2.x,(f16)x2.y,(f16)x2.z,(f16)x2.w,(f16)x3.x,(f16)x3.y,(f16)x3.z,(f16)x3.w};
            *(f16x8*)dst = p0; *(f16x8*)(dst + 8) = p1;
        }
        __syncthreads();   // init barrier
        #pragma unroll 1
        for (int t = 0; t < T_; t++) {
            if (t + 1 < T_) {
                const float* xs = X + (size_t)(t + 1) * (B_ * I_) + (size_t)(b0 + bb) * I_ + seg;
                const float4 x0 = *(const float4*)(xs + 0),  x1 = *(const float4*)(xs + 4);
                const float4 x2 = *(const float4*)(xs + 8),  x3 = *(const float4*)(xs + 12);
                f16* dst = &sh_x[(t + 1) & 1][bb][seg];
                f16x8 p0 = {(f16)x0.x,(f16)x0.y,(f16)x0.z,(f16)x0.w,(f16)x1.x,(f16)x1.y,(f16)x1.z,(f16)x1.w};
                f16x8 p1 = {(f16)x2.x,(f16)x2.y,(f16)x2.z,(f16)x2.w,(f16)x3.x,(f16)x3.y,(f16)x3.z,(f16)x3.w};
                *(f16x8*)dst = p0; *(f16x8*)(dst + 8) = p1;
            }
            __syncthreads();
        }
    }
}

__global__ __launch_bounds__(256) void value_reduce(
    const float* __restrict__ part, const float* __restrict__ bias,
    float* __restrict__ Vout)
{
    const int i = blockIdx.x * 256 + threadIdx.x;   // i < T_*B_
    float s = bias[0];
    #pragma unroll
    for (int sl = 0; sl < NSL; sl++) s += part[(size_t)sl * (T_ * B_) + i];
    Vout[i] = s;
}

extern "C" void kernel_launch(void* const* d_in, const int* in_sizes, int n_in,
                              void* d_out, int out_size, void* d_ws, size_t ws_size,
                              hipStream_t stream) {
    const float* X    = (const float*)d_in[0];
    const float* Wih  = (const float*)d_in[1];
    const float* Whh  = (const float*)d_in[2];
    const float* bih  = (const float*)d_in[3];
    const float* bhh  = (const float*)d_in[4];
    const float* vw   = (const float*)d_in[5];
    const float* bias = (const float*)d_in[6];
    float* Vout = (float*)d_out;

    f16* hbuf = (f16*)d_ws;
    const size_t hbytes    = (size_t)2 * B_ * H_ * sizeof(f16);        // 512 KB
    const size_t flagbytes = (size_t)NBG * 32 * sizeof(unsigned);      // 2 KB (1 line/group)
    unsigned int* flags = (unsigned int*)((char*)d_ws + hbytes);
    float* part = (float*)((char*)d_ws + hbytes + flagbytes);
    const size_t partbytes = (size_t)NSL * T_ * B_ * sizeof(float);    // 16.8 MB
    const int use_part = (ws_size >= hbytes + flagbytes + partbytes) ? 1 : 0;

    hipMemsetAsync(d_ws, 0, hbytes + flagbytes, stream);   // hbuf zeros (t=0) + flags
    if (!use_part)
        hipMemsetAsync(d_out, 0, (size_t)out_size * sizeof(float), stream);

    gru_persistent<<<256, BLOCK, 0, stream>>>(X, Wih, Whh, bih, bhh, vw, bias,
                                              Vout, hbuf, flags, part, use_part);
    if (use_part)
        value_reduce<<<(T_ * B_) / 256, 256, 0, stream>>>(part, bias, Vout);
}

// Round 13
// 1321.628 us; speedup vs baseline: 4.6994x; 1.0787x over previous
//
#include <hip/hip_runtime.h>
#include <hip/hip_fp16.h>

// Persistent fused GRU + value head, MI355X (gfx950).
// T=512,B=256,I=64,H=512. 256 blocks = 16 batch groups x 16 hidden slices.
// R26 = R25/R19 with ONE protocol tweak, zero register cost:
//   PER-BLOCK flag (16 publishers/group) instead of per-wave (32).
//   Tail: per-wave vmcnt(0) ack -> EXISTING __syncthreads (now also joins
//   both MFMA waves' acks) -> tid==0 publishes one flag -> x-GEMM(t+1) ->
//   part store. Poll reads 16 dwords of one line (lane<16).
// Rationale: R22 measured ballot-waits at ~2000+cy even with large slack ->
// dominated by straggler-max over publisher propagation jitter, which grows
// with publisher count. R24's 4-publisher test was confounded by a VGPR
// spill (576-thr blocks); this variant keeps the champion's 192-thr blocks
// and 180-VGPR budget exactly. Ack exposure is free: R13 (exposed) == R19
// (overlapped) within noise.
// HARD RULE (R15/R17): every VMEM-load asm block contains its own s_waitcnt.
// FP order is champion-identical.

#define T_  512
#define B_  256
#define I_  64
#define H_  512
#define NBG 16
#define BT  16                  // batch rows per group
#define HS  32                  // hidden units per block
#define BLOCK 192
#define NSL 32                  // value-head slices (j,wv)

typedef _Float16 f16;
typedef _Float16 f16x8 __attribute__((ext_vector_type(8)));
typedef float    f32x4 __attribute__((ext_vector_type(4)));
typedef unsigned int u32x2 __attribute__((ext_vector_type(2)));

__device__ __forceinline__ float sigmoid_f(float x) { return 1.f / (1.f + __expf(-x)); }
__device__ __forceinline__ float tanh_f(float x) {
    float e2 = __expf(2.f * x);
    return 1.f - 2.f / (e2 + 1.f);
}

__global__ __launch_bounds__(BLOCK, 1) void gru_persistent(
    const float* __restrict__ X, const float* __restrict__ Wih,
    const float* __restrict__ Whh, const float* __restrict__ bih,
    const float* __restrict__ bhh, const float* __restrict__ vw,
    const float* __restrict__ bias, float* __restrict__ Vout,
    f16* __restrict__ hbuf, unsigned int* __restrict__ flags,
    float* __restrict__ part, const int use_part)
{
    const int blk  = blockIdx.x;
    const int g    = (blk & 7) * 2 + (blk >> 7);   // group members share blk%8
    const int j    = (blk >> 3) & 15;
    const int b0   = g * BT;
    const int tid  = threadIdx.x;
    const int wv   = tid >> 6;
    const int lane = tid & 63;
    const int quad = lane >> 4;
    const int mrow = lane & 15;

    __shared__ __align__(16) f16 sh_x[2][BT][I_ + 8];   // X_t ping-pong (f16), padded
    unsigned int* gflags = flags + (size_t)g * 32;       // one 128B line per group

    if (wv < 2) {
        // ============ MFMA waves: weights=A (units on M), h/x=B (batch on N) ============
        // A[m=lane&15 -> unit][k=quad*8+e]; D: row=quad*4+r -> unit, col=lane&15 -> batch
        f16x8 wh[3][16];
        f16x8 wxA[3][2];
        const int um = HS * j + wv * 16 + mrow;
        #pragma unroll
        for (int g3 = 0; g3 < 3; g3++) {
            const size_t grow = (size_t)(g3 * H_ + um);
            #pragma unroll
            for (int kt = 0; kt < 16; kt++) {
                const float* src = Whh + grow * H_ + kt * 32 + quad * 8;
                #pragma unroll
                for (int e = 0; e < 8; e++) wh[g3][kt][e] = (f16)src[e];
            }
            #pragma unroll
            for (int kt = 0; kt < 2; kt++) {
                const float* src = Wih + grow * I_ + kt * 32 + quad * 8;
                #pragma unroll
                for (int e = 0; e < 8; e++) wxA[g3][kt][e] = (f16)src[e];
            }
        }
        float b_r4[4], b_z4[4], b_ni4[4], b_nh4[4], vw4[4];
        #pragma unroll
        for (int r = 0; r < 4; r++) {
            const int ub = HS * j + wv * 16 + quad * 4 + r;
            b_r4[r]  = bih[ub] + bhh[ub];
            b_z4[r]  = bih[H_ + ub] + bhh[H_ + ub];
            b_ni4[r] = bih[2 * H_ + ub];
            b_nh4[r] = bhh[2 * H_ + ub];
            vw4[r]   = vw[ub];
        }
        float hprev[4] = {0.f, 0.f, 0.f, 0.f};   // fp32 anchor for z*h (t=0 zeros)
        unsigned int* blkflag = gflags + j;      // ONE flag per block (16/group)
        const int sl = j * 2 + wv;
        const float bias0 = bias[0];
        const f32x4 zero = {0.f, 0.f, 0.f, 0.f};

        __syncthreads();   // init: service staged X_0 into slot 0

        // ---- x-GEMM for t=0 (slot 0), loop-carried into the first iteration ----
        f32x4 xr, xz, xni;
        {
            f16x8 bx0 = *(const f16x8*)&sh_x[0][mrow][quad * 8];
            f16x8 bx1 = *(const f16x8*)&sh_x[0][mrow][32 + quad * 8];
            xr  = __builtin_amdgcn_mfma_f32_16x16x32_f16(wxA[0][0], bx0, zero, 0, 0, 0);
            xz  = __builtin_amdgcn_mfma_f32_16x16x32_f16(wxA[1][0], bx0, zero, 0, 0, 0);
            xni = __builtin_amdgcn_mfma_f32_16x16x32_f16(wxA[2][0], bx0, zero, 0, 0, 0);
            xr  = __builtin_amdgcn_mfma_f32_16x16x32_f16(wxA[0][1], bx1, xr,  0, 0, 0);
            xz  = __builtin_amdgcn_mfma_f32_16x16x32_f16(wxA[1][1], bx1, xz,  0, 0, 0);
            xni = __builtin_amdgcn_mfma_f32_16x16x32_f16(wxA[2][1], bx1, xni, 0, 0, 0);
        }

        #pragma unroll 1
        for (int t = 0; t < T_; t++) {
            // ---- 1. ballot poll: 16 block-flags in one line (lane<16) ----
            if (t > 0) {
                const unsigned target = (unsigned)t;
                for (;;) {
                    unsigned v = target;
                    if (lane < 16) {
                        const unsigned int* fp = gflags + lane;
                        asm volatile("global_load_dword %0, %1, off sc0 sc1\n\t"
                                     "s_waitcnt vmcnt(0)"
                                     : "=v"(v) : "v"(fp) : "memory");
                    }
                    if (__ballot(v >= target) == ~0ull) break;
                }
            }

            // ---- 2. h_{t-1} fragments: fragment-major slab, 16 x 1KB-contiguous
            //         loads, vmcnt(0) INSIDE the asm (hard rule) ----
            f16x8 afr[16];
            const char* pb = (const char*)(hbuf
                           + ((size_t)((t & 1) ^ 1) * NBG + g) * 8192)
                           + quad * 256 + mrow * 16;
            asm volatile(
                "global_load_dwordx4 %0, %16, off sc0 sc1\n\t"
                "global_load_dwordx4 %1, %16, off offset:1024 sc0 sc1\n\t"
                "global_load_dwordx4 %2, %16, off offset:2048 sc0 sc1\n\t"
                "global_load_dwordx4 %3, %16, off offset:3072 sc0 sc1\n\t"
                "global_load_dwordx4 %4, %17, off sc0 sc1\n\t"
                "global_load_dwordx4 %5, %17, off offset:1024 sc0 sc1\n\t"
                "global_load_dwordx4 %6, %17, off offset:2048 sc0 sc1\n\t"
                "global_load_dwordx4 %7, %17, off offset:3072 sc0 sc1\n\t"
                "global_load_dwordx4 %8, %18, off sc0 sc1\n\t"
                "global_load_dwordx4 %9, %18, off offset:1024 sc0 sc1\n\t"
                "global_load_dwordx4 %10, %18, off offset:2048 sc0 sc1\n\t"
                "global_load_dwordx4 %11, %18, off offset:3072 sc0 sc1\n\t"
                "global_load_dwordx4 %12, %19, off sc0 sc1\n\t"
                "global_load_dwordx4 %13, %19, off offset:1024 sc0 sc1\n\t"
                "global_load_dwordx4 %14, %19, off offset:2048 sc0 sc1\n\t"
                "global_load_dwordx4 %15, %19, off offset:3072 sc0 sc1\n\t"
                "s_waitcnt vmcnt(0)"
                : "=&v"(afr[0]), "=&v"(afr[1]), "=&v"(afr[2]), "=&v"(afr[3]),
                  "=&v"(afr[4]), "=&v"(afr[5]), "=&v"(afr[6]), "=&v"(afr[7]),
                  "=&v"(afr[8]), "=&v"(afr[9]), "=&v"(afr[10]), "=&v"(afr[11]),
                  "=&v"(afr[12]), "=&v"(afr[13]), "=&v"(afr[14]), "=&v"(afr[15])
                : "v"(pb), "v"(pb + 4096), "v"(pb + 8192), "v"(pb + 12288)
                : "memory");

            // ---- 3. h-MFMA chain seeded by the loop-carried x-GEMM result ----
            f32x4 a_r = xr, a_z = xz, a_ni = xni;
            f32x4 a_nh = zero;
            #pragma unroll
            for (int kt = 0; kt < 16; kt++) {
                a_r  = __builtin_amdgcn_mfma_f32_16x16x32_f16(wh[0][kt], afr[kt], a_r,  0, 0, 0);
                a_z  = __builtin_amdgcn_mfma_f32_16x16x32_f16(wh[1][kt], afr[kt], a_z,  0, 0, 0);
                a_nh = __builtin_amdgcn_mfma_f32_16x16x32_f16(wh[2][kt], afr[kt], a_nh, 0, 0, 0);
            }

            // ---- 4. gates in registers; one 8B fragment-major h-store/lane ----
            float hn[4];
            union { f16 h[4]; u32x2 v; } pk;
            #pragma unroll
            for (int r = 0; r < 4; r++) {
                float rg = sigmoid_f(a_r[r] + b_r4[r]);
                float zg = sigmoid_f(a_z[r] + b_z4[r]);
                float ng = tanh_f(a_ni[r] + b_ni4[r] + rg * (a_nh[r] + b_nh4[r]));
                hn[r] = (1.f - zg) * ng + zg * hprev[r];
                hprev[r] = hn[r];
                pk.h[r] = (f16)hn[r];
            }
            {
                // h[batch=mrow][u=32j+16wv+4quad+r] -> idx=(u>>3)*128 + mrow*8 + (u&7)
                f16* hp = hbuf + ((size_t)(t & 1) * NBG + g) * 8192
                        + (size_t)((4 * j + 2 * wv + (quad >> 1)) * 128
                                   + mrow * 8 + (quad & 1) * 4);
                asm volatile("global_store_dwordx2 %0, %1, off sc0 sc1"
                             :: "v"(hp), "v"(pk.v) : "memory");
            }
            // value-head partial overlaps the store's flight time
            float s = hn[0] * vw4[0] + hn[1] * vw4[1] + hn[2] * vw4[2] + hn[3] * vw4[3];
            s += __shfl_xor(s, 16);
            s += __shfl_xor(s, 32);

            // ---- 5. per-wave ack -> barrier joins both waves' acks (and is the
            //         X ping-pong fence) -> ONE flag per block ----
            asm volatile("s_waitcnt vmcnt(0)" ::: "memory");   // own h at MALL
            __syncthreads();                                    // both waves acked
            if (tid == 0)
                __hip_atomic_store(blkflag, (unsigned)(t + 1),
                                   __ATOMIC_RELAXED, __HIP_MEMORY_SCOPE_AGENT);
            __builtin_amdgcn_sched_barrier(0);   // publish before x-GEMM work

            // ---- 6. x-GEMM(t+1) + part store fill the post-publish window ----
            if (t + 1 < T_) {
                f16x8 bx0 = *(const f16x8*)&sh_x[(t + 1) & 1][mrow][quad * 8];
                f16x8 bx1 = *(const f16x8*)&sh_x[(t + 1) & 1][mrow][32 + quad * 8];
                xr  = __builtin_amdgcn_mfma_f32_16x16x32_f16(wxA[0][0], bx0, zero, 0, 0, 0);
                xz  = __builtin_amdgcn_mfma_f32_16x16x32_f16(wxA[1][0], bx0, zero, 0, 0, 0);
                xni = __builtin_amdgcn_mfma_f32_16x16x32_f16(wxA[2][0], bx0, zero, 0, 0, 0);
                xr  = __builtin_amdgcn_mfma_f32_16x16x32_f16(wxA[0][1], bx1, xr,  0, 0, 0);
                xz  = __builtin_amdgcn_mfma_f32_16x16x32_f16(wxA[1][1], bx1, xz,  0, 0, 0);
                xni = __builtin_amdgcn_mfma_f32_16x16x32_f16(wxA[2][1], bx1, xni, 0, 0, 0);
            }
            if (quad == 0) {
                if (use_part) part[(size_t)sl * (T_ * B_) + (size_t)t * B_ + b0 + mrow] = s;
                else atomicAdd(&Vout[(size_t)t * B_ + b0 + mrow], s + (sl == 0 ? bias0 : 0.f));
            }
        }
    } else {
        // ============== service wave: X_{t+1} -> LDS ping-pong (off-path) ==============
        const int bb = lane >> 2, seg = (lane & 3) * 16;
        {   // stage X_0 -> slot 0
            const float* xs = X + (size_t)(b0 + bb) * I_ + seg;
            const float4 x0 = *(const float4*)(xs + 0),  x1 = *(const float4*)(xs + 4);
            const float4 x2 = *(const float4*)(xs + 8),  x3 = *(const float4*)(xs + 12);
            f16* dst = &sh_x[0][bb][seg];
            f16x8 p0 = {(f16)x0.x,(f16)x0.y,(f16)x0.z,(f16)x0.w,(f16)x1.x,(f16)x1.y,(f16)x1.z,(f16)x1.w};
            f16x8 p1 = {(f16)x2.x,(f16)x2.y,(f16)x2.z,(f16)x2.w,(f16)x3.x,(f16)x3.y,(f16)x3.z,(f16)x3.w};
            *(f16x8*)dst = p0; *(f16x8*)(dst + 8) = p1;
        }
        __syncthreads();   // init barrier
        #pragma unroll 1
        for (int t = 0; t < T_; t++) {
            if (t + 1 < T_) {
                const float* xs = X + (size_t)(t + 1) * (B_ * I_) + (size_t)(b0 + bb) * I_ + seg;
                const float4 x0 = *(const float4*)(xs + 0),  x1 = *(const float4*)(xs + 4);
                const float4 x2 = *(const float4*)(xs + 8),  x3 = *(const float4*)(xs + 12);
                f16* dst = &sh_x[(t + 1) & 1][bb][seg];
                f16x8 p0 = {(f16)x0.x,(f16)x0.y,(f16)x0.z,(f16)x0.w,(f16)x1.x,(f16)x1.y,(f16)x1.z,(f16)x1.w};
                f16x8 p1 = {(f16)x2.x,(f16)x2.y,(f16)x2.z,(f16)x2.w,(f16)x3.x,(f16)x3.y,(f16)x3.z,(f16)x3.w};
                *(f16x8*)dst = p0; *(f16x8*)(dst + 8) = p1;
            }
            __syncthreads();
        }
    }
}

__global__ __launch_bounds__(256) void value_reduce(
    const float* __restrict__ part, const float* __restrict__ bias,
    float* __restrict__ Vout)
{
    const int i = blockIdx.x * 256 + threadIdx.x;   // i < T_*B_
    float s = bias[0];
    #pragma unroll
    for (int sl = 0; sl < NSL; sl++) s += part[(size_t)sl * (T_ * B_) + i];
    Vout[i] = s;
}

extern "C" void kernel_launch(void* const* d_in, const int* in_sizes, int n_in,
                              void* d_out, int out_size, void* d_ws, size_t ws_size,
                              hipStream_t stream) {
    const float* X    = (const float*)d_in[0];
    const float* Wih  = (const float*)d_in[1];
    const float* Whh  = (const float*)d_in[2];
    const float* bih  = (const float*)d_in[3];
    const float* bhh  = (const float*)d_in[4];
    const float* vw   = (const float*)d_in[5];
    const float* bias = (const float*)d_in[6];
    float* Vout = (float*)d_out;

    f16* hbuf = (f16*)d_ws;
    const size_t hbytes    = (size_t)2 * B_ * H_ * sizeof(f16);        // 512 KB
    const size_t flagbytes = (size_t)NBG * 32 * sizeof(unsigned);      // 2 KB (1 line/group)
    unsigned int* flags = (unsigned int*)((char*)d_ws + hbytes);
    float* part = (float*)((char*)d_ws + hbytes + flagbytes);
    const size_t partbytes = (size_t)NSL * T_ * B_ * sizeof(float);    // 16.8 MB
    const int use_part = (ws_size >= hbytes + flagbytes + partbytes) ? 1 : 0;

    hipMemsetAsync(d_ws, 0, hbytes + flagbytes, stream);   // hbuf zeros (t=0) + flags
    if (!use_part)
        hipMemsetAsync(d_out, 0, (size_t)out_size * sizeof(float), stream);

    gru_persistent<<<256, BLOCK, 0, stream>>>(X, Wih, Whh, bih, bhh, vw, bias,
                                              Vout, hbuf, flags, part, use_part);
    if (use_part)
        value_reduce<<<(T_ * B_) / 256, 256, 0, stream>>>(part, bias, Vout);
}